// Round 9
// baseline (114.215 us; speedup 1.0000x reference)
//
#include <hip/hip_runtime.h>
#include <stdint.h>

#define NB    128
#define NSTEP 63
#define DT    0.00390625f
#define TSC   2.8853900817779268f   // 2*log2(e): folded into GEMM1 weights/bias

typedef __attribute__((ext_vector_type(8))) short bf16x8;
typedef __attribute__((ext_vector_type(4))) float f32x4;

union Frag { bf16x8 v; uint32_t u[4]; };

__device__ __forceinline__ short f2bf(float f) {
    uint32_t u = __float_as_uint(f);
    u += 0x7FFF + ((u >> 16) & 1);          // round-to-nearest-even
    return (short)(u >> 16);
}

__device__ __forceinline__ uint32_t pk_bf16(float lo, float hi) {
    uint32_t r;
    asm("v_cvt_pk_bf16_f32 %0, %1, %2" : "=v"(r) : "v"(lo), "v"(hi));
    return r;
}

// y = 2*log2e*preact (scale folded into weights): tanh = 1 - 2/(2^y + 1).
// exp-based tanh PROVEN faster than Pade (R8: VALU-issue-bound, TRANS cheap).
// Builtins only (TRANS wait-state hazard: inline-asm exp broke round 3).
__device__ __forceinline__ float tanh_sc(float y) {
    float e = __builtin_amdgcn_exp2f(y);
    return fmaf(-2.0f, __builtin_amdgcn_rcpf(e + 1.0f), 1.0f);
}

// SPLIT-HIDDEN x8: block = 512 threads = 8 waves = one 16-trajectory group.
// Wave wv owns net (wv>>1), hidden half (wv&1) = 32 hidden units.
// Per wave-step: GEMM1 swapped, 2 MFMAs (32 h-cols); tanh x8/lane;
// GEMM2 swapped partial K=32, 1 MFMA (C-in = B2 for half 0, zero for half 1);
// readers sum the two halves. 8192 waves chip-wide = 2x R4 residency.
// Hidden-order permutation makes GEMM1 C-layout == GEMM2 B-frag slots.
// Exchange via double-buffered LDS, 1 barrier/step (R4-proven protocol).
__global__ __launch_bounds__(512, 6) void sde_split8(
    const float* __restrict__ x_real, const float* __restrict__ x_imag,
    const float* __restrict__ params, const float* __restrict__ noise,
    const float* __restrict__ W1, const float* __restrict__ B1,
    const float* __restrict__ W2, const float* __restrict__ B2,
    float* __restrict__ out)
{
    // [dbuf][wave 8][traj 16][20 floats: 16 used + pad 4]
    __shared__ __attribute__((aligned(16))) float xbuf[2][8][16][20];

    const int tid  = threadIdx.x;
    const int lane = tid & 63;
    const int l15  = lane & 15;
    const int g    = lane >> 4;
    const int wv   = tid >> 6;          // 0..7
    const int net  = wv >> 1;
    const int half = wv & 1;            // hidden rows 32*half .. +31

    // ---- GEMM1 A-frags: tile t in {0,1}: h = 32*half + 16t + l15,
    //      elem j -> state feature 8g + j (comps [Re16|Im16]); *TSC ----
    Frag w1f[2];
    #pragma unroll
    for (int t = 0; t < 2; ++t) {
        const int h = 32 * half + 16 * t + l15;
        #pragma unroll
        for (int j = 0; j < 8; ++j)
            w1f[t].v[j] = f2bf(TSC * W1[(net * 38 + 1 + 8 * g + j) * 64 + h]);
    }

    // ---- GEMM2 A-frag: row=l15=d, elem j -> h_local = 16*(j>>2)+4g+(j&3),
    //      global row = 32*half + h_local ----
    Frag w2f;
    #pragma unroll
    for (int j = 0; j < 8; ++j) {
        const int hl = 16 * (j >> 2) + 4 * g + (j & 3);
        w2f.v[j] = f2bf(W2[(net * 64 + 32 * half + hl) * 16 + l15]);
    }

    // ---- bias + t-coefficient at C-layout positions (scaled by TSC) ----
    float pr[5];
    #pragma unroll
    for (int p = 0; p < 5; ++p) pr[p] = params[p];
    f32x4 biascur[2], wtdt[2];
    #pragma unroll
    for (int t = 0; t < 2; ++t) {
        #pragma unroll
        for (int r = 0; r < 4; ++r) {
            const int h = 32 * half + 16 * t + 4 * g + r;
            float b = B1[net * 64 + h];
            #pragma unroll
            for (int p = 0; p < 5; ++p)
                b = fmaf(pr[p], W1[(net * 38 + 33 + p) * 64 + h], b);
            biascur[t][r] = TSC * b;
            wtdt[t][r]    = (TSC * DT) * W1[(net * 38 + 0) * 64 + h];
        }
    }

    // ---- GEMM2 C-in: B2 once (half 0 only) ----
    f32x4 bc;
    #pragma unroll
    for (int r = 0; r < 4; ++r)
        bc[r] = half ? 0.0f : B2[net * 16 + 4 * g + r];

    // ---- state: lane holds comps 8g..8g+7 of traj n (replicated x8 waves) ----
    const int n    = blockIdx.x * 16 + l15;
    const int xrow = n & (NB - 1);
    const float* __restrict__ xsrc = (g < 2) ? x_real : x_imag;
    float st[8];
    #pragma unroll
    for (int i = 0; i < 8; ++i) st[i] = xsrc[xrow * 16 + (g & 1) * 8 + i];

    const float* __restrict__ nsp = noise + (size_t)n * NSTEP;
    float dw = nsp[0];

    float* wrp          = &xbuf[0][wv][l15][4 * g];
    const float* rd_dr0 = &xbuf[0][2 * (g >> 1)][l15][8 * (g & 1)];
    const float* rd_dr1 = &xbuf[0][2 * (g >> 1) + 1][l15][8 * (g & 1)];
    const float* rd_df0 = &xbuf[0][4 + 2 * (g >> 1)][l15][8 * (g & 1)];
    const float* rd_df1 = &xbuf[0][4 + 2 * (g >> 1) + 1][l15][8 * (g & 1)];
    const int dstep = 8 * 16 * 20;   // floats per dbuf half

    for (int s = 0; s < NSTEP; ++s) {
        const float dwn = nsp[(s + 1 < NSTEP) ? s + 1 : s];

        // state -> bf16 B-fragment (k-slot 8g+j = component 8g+j)
        Frag bx;
        bx.u[0] = pk_bf16(st[0], st[1]);
        bx.u[1] = pk_bf16(st[2], st[3]);
        bx.u[2] = pk_bf16(st[4], st[5]);
        bx.u[3] = pk_bf16(st[6], st[7]);

        // GEMM1: 2 MFMAs over this wave's 32 hidden cols
        f32x4 acc0 = __builtin_amdgcn_mfma_f32_16x16x32_bf16(
            w1f[0].v, bx.v, biascur[0], 0, 0, 0);
        f32x4 acc1 = __builtin_amdgcn_mfma_f32_16x16x32_bf16(
            w1f[1].v, bx.v, biascur[1], 0, 0, 0);
        biascur[0] += wtdt[0];
        biascur[1] += wtdt[1];

        // tanh (8 values) -> GEMM2 B-frag; 1 partial MFMA (K=32)
        Frag pb;
        pb.u[0] = pk_bf16(tanh_sc(acc0[0]), tanh_sc(acc0[1]));
        pb.u[1] = pk_bf16(tanh_sc(acc0[2]), tanh_sc(acc0[3]));
        pb.u[2] = pk_bf16(tanh_sc(acc1[0]), tanh_sc(acc1[1]));
        pb.u[3] = pk_bf16(tanh_sc(acc1[2]), tanh_sc(acc1[3]));
        const f32x4 o = __builtin_amdgcn_mfma_f32_16x16x32_bf16(
            w2f.v, pb.v, bc, 0, 0, 0);

        // ---- exchange: write own partial, read+sum all 4 nets' halves ----
        const int db = s & 1;
        *reinterpret_cast<f32x4*>(wrp + db * dstep) = o;
        __syncthreads();
        const float* p0 = rd_dr0 + db * dstep;
        const float* p1 = rd_dr1 + db * dstep;
        const float* q0 = rd_df0 + db * dstep;
        const float* q1 = rd_df1 + db * dstep;
        const f32x4 dr0 = *reinterpret_cast<const f32x4*>(p0)
                        + *reinterpret_cast<const f32x4*>(p1);
        const f32x4 dr1 = *reinterpret_cast<const f32x4*>(p0 + 4)
                        + *reinterpret_cast<const f32x4*>(p1 + 4);
        const f32x4 df0 = *reinterpret_cast<const f32x4*>(q0)
                        + *reinterpret_cast<const f32x4*>(q1);
        const f32x4 df1 = *reinterpret_cast<const f32x4*>(q0 + 4)
                        + *reinterpret_cast<const f32x4*>(q1 + 4);

        // Euler-Maruyama, packed fma
        const f32x4 dt4 = (f32x4)DT;
        const f32x4 dw4 = (f32x4)dw;
        f32x4 stlo = {st[0], st[1], st[2], st[3]};
        f32x4 sthi = {st[4], st[5], st[6], st[7]};
        stlo = __builtin_elementwise_fma(dt4, dr0,
               __builtin_elementwise_fma(dw4, df0, stlo));
        sthi = __builtin_elementwise_fma(dt4, dr1,
               __builtin_elementwise_fma(dw4, df1, sthi));
        #pragma unroll
        for (int i = 0; i < 4; ++i) { st[i] = stlo[i]; st[i + 4] = sthi[i]; }
        dw = dwn;
    }

    // ---- write out (wave 0 only): lane holds comps 8g..8g+7 of traj n ----
    if (wv == 0) {
        float4* op = reinterpret_cast<float4*>(out + (size_t)n * 32 + 8 * g);
        op[0] = make_float4(st[0], st[1], st[2], st[3]);
        op[1] = make_float4(st[4], st[5], st[6], st[7]);
    }
}

extern "C" void kernel_launch(void* const* d_in, const int* in_sizes, int n_in,
                              void* d_out, int out_size, void* d_ws, size_t ws_size,
                              hipStream_t stream) {
    const float* x_real = (const float*)d_in[0];
    const float* x_imag = (const float*)d_in[1];
    const float* params = (const float*)d_in[2];
    const float* noise  = (const float*)d_in[3];
    const float* W1     = (const float*)d_in[4];
    const float* B1     = (const float*)d_in[5];
    const float* W2     = (const float*)d_in[6];
    const float* B2     = (const float*)d_in[7];
    float* out = (float*)d_out;

    // 1024 blocks x 512 threads: 8 waves/block, one 16-traj group per block
    // -> 8192 waves = 32/CU = 2x R4 residency
    sde_split8<<<dim3(1024), dim3(512), 0, stream>>>(
        x_real, x_imag, params, noise, W1, B1, W2, B2, out);
}

// Round 10
// 105.282 us; speedup vs baseline: 1.0848x; 1.0848x over previous
//
#include <hip/hip_runtime.h>
#include <stdint.h>

#define NB    128
#define NSTEP 63
#define DT    0.00390625f
#define TSC   2.8853900817779268f   // 2*log2(e): folded into GEMM1 weights

typedef __attribute__((ext_vector_type(8))) short bf16x8;
typedef __attribute__((ext_vector_type(4))) float f32x4;

union Frag { bf16x8 v; uint32_t u[4]; };

__device__ __forceinline__ short f2bf(float f) {
    uint32_t u = __float_as_uint(f);
    u += 0x7FFF + ((u >> 16) & 1);          // round-to-nearest-even
    return (short)(u >> 16);
}

__device__ __forceinline__ uint32_t pk_bf16(float lo, float hi) {
    uint32_t r;
    asm("v_cvt_pk_bf16_f32 %0, %1, %2" : "=v"(r) : "v"(lo), "v"(hi));
    return r;
}

// y = 2*log2e*preact (scale folded into weights): tanh = 1 - 2/(2^y + 1).
// exp-tanh PROVEN best (R8: Pade's VALU cost > TRANS savings). Builtins only
// (TRANS wait-state hazard: inline-asm exp broke round 3).
__device__ __forceinline__ float tanh_sc(float y) {
    float e = __builtin_amdgcn_exp2f(y);
    return fmaf(-2.0f, __builtin_amdgcn_rcpf(e + 1.0f), 1.0f);
}

// Round-4 structure (best: 83.4 us) + EXPLICIT PHASE STAGGER.
// All waves run identical code -> co-resident blocks on a CU hit the TRANS
// (tanh) burst simultaneously: TRANS saturates while VALU idles, then vice
// versa. The stagger prologue skews co-resident blocks by ~0/200/400/600 cyc
// (uniform within a block; varies at both +1 and +256 blockIdx strides to
// cover either co-residency mapping) so pipe bursts interleave across waves.
__global__ __launch_bounds__(256, 4) void sde_stag(
    const float* __restrict__ x_real, const float* __restrict__ x_imag,
    const float* __restrict__ params, const float* __restrict__ noise,
    const float* __restrict__ W1, const float* __restrict__ B1,
    const float* __restrict__ W2, const float* __restrict__ B2,
    float* __restrict__ out)
{
    // [dbuf][net 4][traj 16][20 floats: d 0..15 used, pad 4]
    __shared__ __attribute__((aligned(16))) float xbuf[2][4][16][20];

    const int tid  = threadIdx.x;
    const int lane = tid & 63;
    const int l15  = lane & 15;
    const int g    = lane >> 4;
    const int wv   = tid >> 6;          // net index 0..3

    // ---- GEMM1 A-frags: tile t, row=l15 -> h = 16t + l15 (within net wv),
    //      elem j -> state feature 8g + j; pre-scaled by TSC ----
    Frag w1f[4];
    #pragma unroll
    for (int t = 0; t < 4; ++t) {
        const int h = 16 * t + l15;
        #pragma unroll
        for (int j = 0; j < 8; ++j)
            w1f[t].v[j] = f2bf(TSC * W1[(wv * 38 + 1 + 8 * g + j) * 64 + h]);
    }

    // ---- GEMM2 A-frags: row=l15=d, elem j -> h_local = 16*(2kt+(j>>2)) + 4g + (j&3) ----
    Frag w2f[2];
    #pragma unroll
    for (int kt = 0; kt < 2; ++kt) {
        #pragma unroll
        for (int j = 0; j < 8; ++j) {
            const int hl = 16 * (2 * kt + (j >> 2)) + 4 * g + (j & 3);
            w2f[kt].v[j] = f2bf(W2[(wv * 64 + hl) * 16 + l15]);
        }
    }

    // ---- bias + t-coefficient at C-layout positions (scaled by TSC) ----
    float pr[5];
    #pragma unroll
    for (int p = 0; p < 5; ++p) pr[p] = params[p];
    f32x4 biascur[4], wtdt[4];
    #pragma unroll
    for (int t = 0; t < 4; ++t) {
        #pragma unroll
        for (int r = 0; r < 4; ++r) {
            const int h = 16 * t + 4 * g + r;
            float b = B1[wv * 64 + h];
            #pragma unroll
            for (int p = 0; p < 5; ++p)
                b = fmaf(pr[p], W1[(wv * 38 + 33 + p) * 64 + h], b);
            biascur[t][r] = TSC * b;
            wtdt[t][r]    = (TSC * DT) * W1[(wv * 38 + 0) * 64 + h];
        }
    }

    // ---- B2 C-in: row 4g+r = output dim d ----
    f32x4 bc;
    #pragma unroll
    for (int r = 0; r < 4; ++r) bc[r] = B2[wv * 16 + 4 * g + r];

    // ---- state: lane holds comps 8g..8g+7 of traj n (replicated across waves) ----
    const int n    = blockIdx.x * 16 + l15;
    const int xrow = n & (NB - 1);
    const float* __restrict__ xsrc = (g < 2) ? x_real : x_imag;
    float st[8];
    #pragma unroll
    for (int i = 0; i < 8; ++i) st[i] = xsrc[xrow * 16 + (g & 1) * 8 + i];

    const float* __restrict__ nsp = noise + (size_t)n * NSTEP;
    float dw = nsp[0];

    // ---- PHASE STAGGER: dependent-rcp delay chain, ~200 cyc per phase unit.
    //      asm-volatile keeps the chain live (rule: DCE via unused result) ----
    {
        const int phase = ((blockIdx.x >> 8) + blockIdx.x) & 3;
        float xx = 2.0f + (float)l15;
        for (int i = 0; i < phase * 16; ++i)
            xx = __builtin_amdgcn_rcpf(xx + 0.25f);
        asm volatile("" :: "v"(xx));
    }

    float* wrp           = &xbuf[0][wv][l15][4 * g];
    const float* rd_dr   = &xbuf[0][g >> 1][l15][8 * (g & 1)];
    const float* rd_df   = &xbuf[0][2 + (g >> 1)][l15][8 * (g & 1)];
    const int dstep = 4 * 16 * 20;   // floats per dbuf half

    for (int s = 0; s < NSTEP; ++s) {
        const float dwn = nsp[(s + 1 < NSTEP) ? s + 1 : s];

        // state -> bf16 B-fragment (k-slot 8g+j = component 8g+j)
        Frag bx;
        bx.u[0] = pk_bf16(st[0], st[1]);
        bx.u[1] = pk_bf16(st[2], st[3]);
        bx.u[2] = pk_bf16(st[4], st[5]);
        bx.u[3] = pk_bf16(st[6], st[7]);

        // GEMM1: 4 MFMAs, C-in = scaled bias + t*w_t
        f32x4 acc[4];
        #pragma unroll
        for (int t = 0; t < 4; ++t)
            acc[t] = __builtin_amdgcn_mfma_f32_16x16x32_bf16(
                w1f[t].v, bx.v, biascur[t], 0, 0, 0);
        #pragma unroll
        for (int t = 0; t < 4; ++t) biascur[t] += wtdt[t];

        // GEMM2: K=64 over own net's hidden, output = own net's 16 dims
        f32x4 o = bc;
        #pragma unroll
        for (int kt = 0; kt < 2; ++kt) {
            const float t0 = tanh_sc(acc[2 * kt][0]);
            const float t1 = tanh_sc(acc[2 * kt][1]);
            const float t2 = tanh_sc(acc[2 * kt][2]);
            const float t3 = tanh_sc(acc[2 * kt][3]);
            const float t4 = tanh_sc(acc[2 * kt + 1][0]);
            const float t5 = tanh_sc(acc[2 * kt + 1][1]);
            const float t6 = tanh_sc(acc[2 * kt + 1][2]);
            const float t7 = tanh_sc(acc[2 * kt + 1][3]);
            Frag pb;
            pb.u[0] = pk_bf16(t0, t1);  pb.u[1] = pk_bf16(t2, t3);
            pb.u[2] = pk_bf16(t4, t5);  pb.u[3] = pk_bf16(t6, t7);
            o = __builtin_amdgcn_mfma_f32_16x16x32_bf16(w2f[kt].v, pb.v, o, 0, 0, 0);
        }

        // ---- exchange: write own net's 4 outputs, read all 4 nets ----
        const int db = s & 1;
        *reinterpret_cast<f32x4*>(wrp + db * dstep) = o;
        __syncthreads();
        const float* dp = rd_dr + db * dstep;
        const float* fp = rd_df + db * dstep;
        const f32x4 dr0 = *reinterpret_cast<const f32x4*>(dp);
        const f32x4 dr1 = *reinterpret_cast<const f32x4*>(dp + 4);
        const f32x4 df0 = *reinterpret_cast<const f32x4*>(fp);
        const f32x4 df1 = *reinterpret_cast<const f32x4*>(fp + 4);

        #pragma unroll
        for (int i = 0; i < 4; ++i) {
            st[i]     = fmaf(DT, dr0[i], fmaf(dw, df0[i], st[i]));
            st[i + 4] = fmaf(DT, dr1[i], fmaf(dw, df1[i], st[i + 4]));
        }
        dw = dwn;
    }

    // ---- write out (wave 0 only): lane holds comps 8g..8g+7 of traj n ----
    if (wv == 0) {
        float4* op = reinterpret_cast<float4*>(out + (size_t)n * 32 + 8 * g);
        op[0] = make_float4(st[0], st[1], st[2], st[3]);
        op[1] = make_float4(st[4], st[5], st[6], st[7]);
    }
}

extern "C" void kernel_launch(void* const* d_in, const int* in_sizes, int n_in,
                              void* d_out, int out_size, void* d_ws, size_t ws_size,
                              hipStream_t stream) {
    const float* x_real = (const float*)d_in[0];
    const float* x_imag = (const float*)d_in[1];
    const float* params = (const float*)d_in[2];
    const float* noise  = (const float*)d_in[3];
    const float* W1     = (const float*)d_in[4];
    const float* B1     = (const float*)d_in[5];
    const float* W2     = (const float*)d_in[6];
    const float* B2     = (const float*)d_in[7];
    float* out = (float*)d_out;

    // 1024 blocks x 256 threads: 4 waves/block, one 16-traj group per block
    sde_stag<<<dim3(1024), dim3(256), 0, stream>>>(
        x_real, x_imag, params, noise, W1, B1, W2, B2, out);
}

// Round 11
// 105.199 us; speedup vs baseline: 1.0857x; 1.0008x over previous
//
#include <hip/hip_runtime.h>
#include <stdint.h>

#define NB    128
#define NSTEP 63
#define DT    0.00390625f
#define TSC   2.8853900817779268f   // 2*log2(e): folded into GEMM1 weights

typedef __attribute__((ext_vector_type(8))) short bf16x8;
typedef __attribute__((ext_vector_type(4))) float f32x4;

union Frag { bf16x8 v; uint32_t u[4]; };

__device__ __forceinline__ short f2bf(float f) {
    uint32_t u = __float_as_uint(f);
    u += 0x7FFF + ((u >> 16) & 1);          // round-to-nearest-even
    return (short)(u >> 16);
}

__device__ __forceinline__ uint32_t pk_bf16(float lo, float hi) {
    uint32_t r;
    asm("v_cvt_pk_bf16_f32 %0, %1, %2" : "=v"(r) : "v"(lo), "v"(hi));
    return r;
}

// u = 1/(2^y + 1) with y = 2*log2e*preact (TSC folded into GEMM1 weights).
// tanh = 1 - 2u; the affine part is folded into GEMM2: W2' = -2*W2,
// C-in' = B2 + sum_h W2[h,:]. Saves the per-value fma vs tanh_sc (R4).
// Builtins only (TRANS wait-state hazard: inline-asm exp broke round 3).
__device__ __forceinline__ float sig_u(float y) {
    float e = __builtin_amdgcn_exp2f(y);
    return __builtin_amdgcn_rcpf(e + 1.0f);
}

// Round-4 structure (best: 83.4 us) + instruction diet (R11):
//  - tanh affine fold into GEMM2 weights/bias (-16 VALU/lane-step)
//  - packed v_pk_fma state update (-8 VALU/lane-step)
// Block = 256 threads = 4 waves = one 16-trajectory group; wave wv owns net
// wv. GEMM1 swapped (4 MFMAs, 64 h-cols), u-activation, GEMM2 swapped dense
// K=64 (2 MFMAs). Hidden-order permutation makes GEMM1 C-layout registers
// bit-identical to GEMM2 B-frag slots. Exchange via double-buffered LDS,
// 1 barrier/step; replicated state is bitwise identical across waves.
__global__ __launch_bounds__(256, 4) void sde_diet(
    const float* __restrict__ x_real, const float* __restrict__ x_imag,
    const float* __restrict__ params, const float* __restrict__ noise,
    const float* __restrict__ W1, const float* __restrict__ B1,
    const float* __restrict__ W2, const float* __restrict__ B2,
    float* __restrict__ out)
{
    // [dbuf][net 4][traj 16][20 floats: d 0..15 used, pad 4]
    __shared__ __attribute__((aligned(16))) float xbuf[2][4][16][20];

    const int tid  = threadIdx.x;
    const int lane = tid & 63;
    const int l15  = lane & 15;
    const int g    = lane >> 4;
    const int wv   = tid >> 6;          // net index 0..3

    // ---- GEMM1 A-frags: tile t, row=l15 -> h = 16t + l15 (within net wv),
    //      elem j -> state feature 8g + j; pre-scaled by TSC ----
    Frag w1f[4];
    #pragma unroll
    for (int t = 0; t < 4; ++t) {
        const int h = 16 * t + l15;
        #pragma unroll
        for (int j = 0; j < 8; ++j)
            w1f[t].v[j] = f2bf(TSC * W1[(wv * 38 + 1 + 8 * g + j) * 64 + h]);
    }

    // ---- GEMM2 A-frags (W2' = -2*W2): row=l15=d,
    //      elem j -> h_local = 16*(2kt+(j>>2)) + 4g + (j&3) ----
    Frag w2f[2];
    #pragma unroll
    for (int kt = 0; kt < 2; ++kt) {
        #pragma unroll
        for (int j = 0; j < 8; ++j) {
            const int hl = 16 * (2 * kt + (j >> 2)) + 4 * g + (j & 3);
            w2f[kt].v[j] = f2bf(-2.0f * W2[(wv * 64 + hl) * 16 + l15]);
        }
    }

    // ---- bias + t-coefficient at C-layout positions (scaled by TSC) ----
    float pr[5];
    #pragma unroll
    for (int p = 0; p < 5; ++p) pr[p] = params[p];
    f32x4 biascur[4], wtdt[4];
    #pragma unroll
    for (int t = 0; t < 4; ++t) {
        #pragma unroll
        for (int r = 0; r < 4; ++r) {
            const int h = 16 * t + 4 * g + r;
            float b = B1[wv * 64 + h];
            #pragma unroll
            for (int p = 0; p < 5; ++p)
                b = fmaf(pr[p], W1[(wv * 38 + 33 + p) * 64 + h], b);
            biascur[t][r] = TSC * b;
            wtdt[t][r]    = (TSC * DT) * W1[(wv * 38 + 0) * 64 + h];
        }
    }

    // ---- GEMM2 C-in': B2 + sum_h W2[h, 4g..4g+3] (tanh affine fold) ----
    f32x4 bc;
    #pragma unroll
    for (int r = 0; r < 4; ++r) bc[r] = B2[wv * 16 + 4 * g + r];
    #pragma unroll 8
    for (int h = 0; h < 64; ++h)
        bc += *reinterpret_cast<const f32x4*>(&W2[(wv * 64 + h) * 16 + 4 * g]);

    // ---- state: lane holds comps 8g..8g+7 of traj n (replicated across waves) ----
    const int n    = blockIdx.x * 16 + l15;
    const int xrow = n & (NB - 1);
    const float* __restrict__ xsrc = (g < 2) ? x_real : x_imag;
    const int xoff = (g & 1) * 8;
    f32x4 stlo = *reinterpret_cast<const f32x4*>(&xsrc[xrow * 16 + xoff]);
    f32x4 sthi = *reinterpret_cast<const f32x4*>(&xsrc[xrow * 16 + xoff + 4]);

    const float* __restrict__ nsp = noise + (size_t)n * NSTEP;
    float dw = nsp[0];

    float* wrp           = &xbuf[0][wv][l15][4 * g];
    const float* rd_dr   = &xbuf[0][g >> 1][l15][8 * (g & 1)];
    const float* rd_df   = &xbuf[0][2 + (g >> 1)][l15][8 * (g & 1)];
    const int dstep = 4 * 16 * 20;   // floats per dbuf half

    for (int s = 0; s < NSTEP; ++s) {
        const float dwn = nsp[(s + 1 < NSTEP) ? s + 1 : s];

        // state -> bf16 B-fragment (k-slot 8g+j = component 8g+j)
        Frag bx;
        bx.u[0] = pk_bf16(stlo[0], stlo[1]);
        bx.u[1] = pk_bf16(stlo[2], stlo[3]);
        bx.u[2] = pk_bf16(sthi[0], sthi[1]);
        bx.u[3] = pk_bf16(sthi[2], sthi[3]);

        // GEMM1: 4 MFMAs, C-in = scaled bias + t*w_t
        f32x4 acc[4];
        #pragma unroll
        for (int t = 0; t < 4; ++t)
            acc[t] = __builtin_amdgcn_mfma_f32_16x16x32_bf16(
                w1f[t].v, bx.v, biascur[t], 0, 0, 0);
        #pragma unroll
        for (int t = 0; t < 4; ++t) biascur[t] += wtdt[t];

        // GEMM2: u-activation (exp+add+rcp, no fma), K=64 over own net
        f32x4 o = bc;
        #pragma unroll
        for (int kt = 0; kt < 2; ++kt) {
            const float u0 = sig_u(acc[2 * kt][0]);
            const float u1 = sig_u(acc[2 * kt][1]);
            const float u2 = sig_u(acc[2 * kt][2]);
            const float u3 = sig_u(acc[2 * kt][3]);
            const float u4 = sig_u(acc[2 * kt + 1][0]);
            const float u5 = sig_u(acc[2 * kt + 1][1]);
            const float u6 = sig_u(acc[2 * kt + 1][2]);
            const float u7 = sig_u(acc[2 * kt + 1][3]);
            Frag pb;
            pb.u[0] = pk_bf16(u0, u1);  pb.u[1] = pk_bf16(u2, u3);
            pb.u[2] = pk_bf16(u4, u5);  pb.u[3] = pk_bf16(u6, u7);
            o = __builtin_amdgcn_mfma_f32_16x16x32_bf16(w2f[kt].v, pb.v, o, 0, 0, 0);
        }

        // ---- exchange: write own net's 4 outputs, read all 4 nets ----
        const int db = s & 1;
        *reinterpret_cast<f32x4*>(wrp + db * dstep) = o;
        __syncthreads();
        const float* dp = rd_dr + db * dstep;
        const float* fp = rd_df + db * dstep;
        const f32x4 dr0 = *reinterpret_cast<const f32x4*>(dp);
        const f32x4 dr1 = *reinterpret_cast<const f32x4*>(dp + 4);
        const f32x4 df0 = *reinterpret_cast<const f32x4*>(fp);
        const f32x4 df1 = *reinterpret_cast<const f32x4*>(fp + 4);

        // Euler-Maruyama, packed v_pk_fma
        const f32x4 dt4 = (f32x4)DT;
        const f32x4 dw4 = (f32x4)dw;
        stlo = __builtin_elementwise_fma(dt4, dr0,
               __builtin_elementwise_fma(dw4, df0, stlo));
        sthi = __builtin_elementwise_fma(dt4, dr1,
               __builtin_elementwise_fma(dw4, df1, sthi));
        dw = dwn;
    }

    // ---- write out (wave 0 only): lane holds comps 8g..8g+7 of traj n ----
    if (wv == 0) {
        float4* op = reinterpret_cast<float4*>(out + (size_t)n * 32 + 8 * g);
        op[0] = make_float4(stlo[0], stlo[1], stlo[2], stlo[3]);
        op[1] = make_float4(sthi[0], sthi[1], sthi[2], sthi[3]);
    }
}

extern "C" void kernel_launch(void* const* d_in, const int* in_sizes, int n_in,
                              void* d_out, int out_size, void* d_ws, size_t ws_size,
                              hipStream_t stream) {
    const float* x_real = (const float*)d_in[0];
    const float* x_imag = (const float*)d_in[1];
    const float* params = (const float*)d_in[2];
    const float* noise  = (const float*)d_in[3];
    const float* W1     = (const float*)d_in[4];
    const float* B1     = (const float*)d_in[5];
    const float* W2     = (const float*)d_in[6];
    const float* B2     = (const float*)d_in[7];
    float* out = (float*)d_out;

    // 1024 blocks x 256 threads: 4 waves/block, one 16-traj group per block
    sde_diet<<<dim3(1024), dim3(256), 0, stream>>>(
        x_real, x_imag, params, noise, W1, B1, W2, B2, out);
}

// Round 12
// 81.169 us; speedup vs baseline: 1.4071x; 1.2961x over previous
//
#include <hip/hip_runtime.h>
#include <stdint.h>

#define NB    128
#define NSTEP 63
#define DT    0.00390625f
#define TSC   2.8853900817779268f   // 2*log2(e): folded into GEMM1 weights

typedef __attribute__((ext_vector_type(8))) short bf16x8;
typedef __attribute__((ext_vector_type(4))) float f32x4;

union Frag { bf16x8 v; uint32_t u[4]; };

__device__ __forceinline__ short f2bf(float f) {
    uint32_t u = __float_as_uint(f);
    u += 0x7FFF + ((u >> 16) & 1);          // round-to-nearest-even
    return (short)(u >> 16);
}

__device__ __forceinline__ uint32_t pk_bf16(float lo, float hi) {
    uint32_t r;
    asm("v_cvt_pk_bf16_f32 %0, %1, %2" : "=v"(r) : "v"(lo), "v"(hi));
    return r;
}

// u = 1/(2^y + 1) with y = 2*log2e*preact (TSC folded into GEMM1 weights).
// tanh = 1 - 2u; affine part folded into GEMM2 (W2' = -2*W2, C-in' = B2 +
// sum_h W2[h,:], the sum computed by 2 init MFMAs -- NO per-thread load loop:
// R11's 64-load prologue herd destroyed the lockstep L2 noise streaming,
// FETCH 4.8->35MB). Builtins only (inline-asm exp broke round 3).
__device__ __forceinline__ float sig_u(float y) {
    float e = __builtin_amdgcn_exp2f(y);
    return __builtin_amdgcn_rcpf(e + 1.0f);
}

// Round-4 structure (best clean run: 83.4 us) + instruction diet:
//  - tanh affine fold into GEMM2 weights/bias (-16 VALU/lane-step)
//  - packed v_pk_fma state update (-8 VALU/lane-step)
//  - bc column-sum via 2 init MFMAs (keeps prologue light; no load herd)
// Block = 256 threads = 4 waves = one 16-trajectory group; wave wv owns net
// wv. GEMM1 swapped (4 MFMAs, 64 h-cols), u-activation, GEMM2 swapped dense
// K=64 (2 MFMAs). Hidden-order permutation makes GEMM1 C-layout registers
// bit-identical to GEMM2 B-frag slots. Exchange via double-buffered LDS,
// 1 barrier/step; replicated state is bitwise identical across waves.
__global__ __launch_bounds__(256, 4) void sde_diet2(
    const float* __restrict__ x_real, const float* __restrict__ x_imag,
    const float* __restrict__ params, const float* __restrict__ noise,
    const float* __restrict__ W1, const float* __restrict__ B1,
    const float* __restrict__ W2, const float* __restrict__ B2,
    float* __restrict__ out)
{
    // [dbuf][net 4][traj 16][20 floats: d 0..15 used, pad 4]
    __shared__ __attribute__((aligned(16))) float xbuf[2][4][16][20];

    const int tid  = threadIdx.x;
    const int lane = tid & 63;
    const int l15  = lane & 15;
    const int g    = lane >> 4;
    const int wv   = tid >> 6;          // net index 0..3

    // ---- GEMM1 A-frags: tile t, row=l15 -> h = 16t + l15 (within net wv),
    //      elem j -> state feature 8g + j; pre-scaled by TSC ----
    Frag w1f[4];
    #pragma unroll
    for (int t = 0; t < 4; ++t) {
        const int h = 16 * t + l15;
        #pragma unroll
        for (int j = 0; j < 8; ++j)
            w1f[t].v[j] = f2bf(TSC * W1[(wv * 38 + 1 + 8 * g + j) * 64 + h]);
    }

    // ---- GEMM2 A-frags (W2' = -2*W2): row=l15=d,
    //      elem j -> h_local = 16*(2kt+(j>>2)) + 4g + (j&3) ----
    Frag w2f[2];
    #pragma unroll
    for (int kt = 0; kt < 2; ++kt) {
        #pragma unroll
        for (int j = 0; j < 8; ++j) {
            const int hl = 16 * (2 * kt + (j >> 2)) + 4 * g + (j & 3);
            w2f[kt].v[j] = f2bf(-2.0f * W2[(wv * 64 + hl) * 16 + l15]);
        }
    }

    // ---- bias + t-coefficient at C-layout positions (scaled by TSC) ----
    float pr[5];
    #pragma unroll
    for (int p = 0; p < 5; ++p) pr[p] = params[p];
    f32x4 biascur[4], wtdt[4];
    #pragma unroll
    for (int t = 0; t < 4; ++t) {
        #pragma unroll
        for (int r = 0; r < 4; ++r) {
            const int h = 16 * t + 4 * g + r;
            float b = B1[wv * 64 + h];
            #pragma unroll
            for (int p = 0; p < 5; ++p)
                b = fmaf(pr[p], W1[(wv * 38 + 33 + p) * 64 + h], b);
            biascur[t][r] = TSC * b;
            wtdt[t][r]    = (TSC * DT) * W1[(wv * 38 + 0) * 64 + h];
        }
    }

    // ---- GEMM2 C-in': B2 + sum_h W2[h, d], computed by 2 MFMAs with a
    //      constant B-frag of -0.5: sum_h(-2*W2)*(-0.5) = sum_h W2 ----
    f32x4 bc;
    #pragma unroll
    for (int r = 0; r < 4; ++r) bc[r] = B2[wv * 16 + 4 * g + r];
    {
        Frag nh;
        nh.u[0] = 0xBF00BF00u;  nh.u[1] = 0xBF00BF00u;   // bf16 -0.5 x2
        nh.u[2] = 0xBF00BF00u;  nh.u[3] = 0xBF00BF00u;
        bc = __builtin_amdgcn_mfma_f32_16x16x32_bf16(w2f[0].v, nh.v, bc, 0, 0, 0);
        bc = __builtin_amdgcn_mfma_f32_16x16x32_bf16(w2f[1].v, nh.v, bc, 0, 0, 0);
    }

    // ---- state: lane holds comps 8g..8g+7 of traj n (replicated across waves) ----
    const int n    = blockIdx.x * 16 + l15;
    const int xrow = n & (NB - 1);
    const float* __restrict__ xsrc = (g < 2) ? x_real : x_imag;
    const int xoff = (g & 1) * 8;
    f32x4 stlo = *reinterpret_cast<const f32x4*>(&xsrc[xrow * 16 + xoff]);
    f32x4 sthi = *reinterpret_cast<const f32x4*>(&xsrc[xrow * 16 + xoff + 4]);

    const float* __restrict__ nsp = noise + (size_t)n * NSTEP;
    float dw = nsp[0];

    float* wrp           = &xbuf[0][wv][l15][4 * g];
    const float* rd_dr   = &xbuf[0][g >> 1][l15][8 * (g & 1)];
    const float* rd_df   = &xbuf[0][2 + (g >> 1)][l15][8 * (g & 1)];
    const int dstep = 4 * 16 * 20;   // floats per dbuf half

    for (int s = 0; s < NSTEP; ++s) {
        const float dwn = nsp[(s + 1 < NSTEP) ? s + 1 : s];

        // state -> bf16 B-fragment (k-slot 8g+j = component 8g+j)
        Frag bx;
        bx.u[0] = pk_bf16(stlo[0], stlo[1]);
        bx.u[1] = pk_bf16(stlo[2], stlo[3]);
        bx.u[2] = pk_bf16(sthi[0], sthi[1]);
        bx.u[3] = pk_bf16(sthi[2], sthi[3]);

        // GEMM1: 4 MFMAs, C-in = scaled bias + t*w_t
        f32x4 acc[4];
        #pragma unroll
        for (int t = 0; t < 4; ++t)
            acc[t] = __builtin_amdgcn_mfma_f32_16x16x32_bf16(
                w1f[t].v, bx.v, biascur[t], 0, 0, 0);
        #pragma unroll
        for (int t = 0; t < 4; ++t) biascur[t] += wtdt[t];

        // GEMM2: u-activation (exp+add+rcp, no fma), K=64 over own net
        f32x4 o = bc;
        #pragma unroll
        for (int kt = 0; kt < 2; ++kt) {
            const float u0 = sig_u(acc[2 * kt][0]);
            const float u1 = sig_u(acc[2 * kt][1]);
            const float u2 = sig_u(acc[2 * kt][2]);
            const float u3 = sig_u(acc[2 * kt][3]);
            const float u4 = sig_u(acc[2 * kt + 1][0]);
            const float u5 = sig_u(acc[2 * kt + 1][1]);
            const float u6 = sig_u(acc[2 * kt + 1][2]);
            const float u7 = sig_u(acc[2 * kt + 1][3]);
            Frag pb;
            pb.u[0] = pk_bf16(u0, u1);  pb.u[1] = pk_bf16(u2, u3);
            pb.u[2] = pk_bf16(u4, u5);  pb.u[3] = pk_bf16(u6, u7);
            o = __builtin_amdgcn_mfma_f32_16x16x32_bf16(w2f[kt].v, pb.v, o, 0, 0, 0);
        }

        // ---- exchange: write own net's 4 outputs, read all 4 nets ----
        const int db = s & 1;
        *reinterpret_cast<f32x4*>(wrp + db * dstep) = o;
        __syncthreads();
        const float* dp = rd_dr + db * dstep;
        const float* fp = rd_df + db * dstep;
        const f32x4 dr0 = *reinterpret_cast<const f32x4*>(dp);
        const f32x4 dr1 = *reinterpret_cast<const f32x4*>(dp + 4);
        const f32x4 df0 = *reinterpret_cast<const f32x4*>(fp);
        const f32x4 df1 = *reinterpret_cast<const f32x4*>(fp + 4);

        // Euler-Maruyama, packed v_pk_fma
        const f32x4 dt4 = (f32x4)DT;
        const f32x4 dw4 = (f32x4)dw;
        stlo = __builtin_elementwise_fma(dt4, dr0,
               __builtin_elementwise_fma(dw4, df0, stlo));
        sthi = __builtin_elementwise_fma(dt4, dr1,
               __builtin_elementwise_fma(dw4, df1, sthi));
        dw = dwn;
    }

    // ---- write out (wave 0 only): lane holds comps 8g..8g+7 of traj n ----
    if (wv == 0) {
        float4* op = reinterpret_cast<float4*>(out + (size_t)n * 32 + 8 * g);
        op[0] = make_float4(stlo[0], stlo[1], stlo[2], stlo[3]);
        op[1] = make_float4(sthi[0], sthi[1], sthi[2], sthi[3]);
    }
}

extern "C" void kernel_launch(void* const* d_in, const int* in_sizes, int n_in,
                              void* d_out, int out_size, void* d_ws, size_t ws_size,
                              hipStream_t stream) {
    const float* x_real = (const float*)d_in[0];
    const float* x_imag = (const float*)d_in[1];
    const float* params = (const float*)d_in[2];
    const float* noise  = (const float*)d_in[3];
    const float* W1     = (const float*)d_in[4];
    const float* B1     = (const float*)d_in[5];
    const float* W2     = (const float*)d_in[6];
    const float* B2     = (const float*)d_in[7];
    float* out = (float*)d_out;

    // 1024 blocks x 256 threads: 4 waves/block, one 16-traj group per block
    sde_diet2<<<dim3(1024), dim3(256), 0, stream>>>(
        x_real, x_imag, params, noise, W1, B1, W2, B2, out);
}

// Round 13
// 78.160 us; speedup vs baseline: 1.4613x; 1.0385x over previous
//
#include <hip/hip_runtime.h>
#include <stdint.h>

#define NB    128
#define NSTEP 63
#define DT    0.00390625f
#define TSC   2.8853900817779268f   // 2*log2(e): folded into GEMM1 weights

typedef __attribute__((ext_vector_type(8))) short bf16x8;
typedef __attribute__((ext_vector_type(4))) float f32x4;

union Frag { bf16x8 v; uint32_t u[4]; };

__device__ __forceinline__ short f2bf(float f) {
    uint32_t u = __float_as_uint(f);
    u += 0x7FFF + ((u >> 16) & 1);          // round-to-nearest-even
    return (short)(u >> 16);
}

__device__ __forceinline__ uint32_t pk_bf16(float lo, float hi) {
    uint32_t r;
    asm("v_cvt_pk_bf16_f32 %0, %1, %2" : "=v"(r) : "v"(lo), "v"(hi));
    return r;
}

// u = 1/(2^y + 1) with y = 2*log2e*preact (TSC folded into GEMM1 weights).
// tanh = 1 - 2u; affine part folded into GEMM2 (W2' = -2*W2, C-in' = B2 +
// sum_h W2[h,:] via 2 init MFMAs). Builtins only (inline-asm exp broke R3).
__device__ __forceinline__ float sig_u(float y) {
    float e = __builtin_amdgcn_exp2f(y);
    return __builtin_amdgcn_rcpf(e + 1.0f);
}

// R12 (81.2 us) + NOISE LDS STAGING:
// the only per-step global access was noise[n*63+s] -- a 16-cacheline
// scatter per wave-load (lane l15 -> traj n, stride 252B). Stage each
// block's 4KB noise slice in LDS once (coalesced), transposed to
// nl[s][traj] (stride-16 rows: conflict-free, 4-way broadcast), row 63
// duplicated from 62 so the next-dw read needs no clamp. Per-step cost:
// one conflict-free ds_read_b32.
__global__ __launch_bounds__(256, 4) void sde_nlds(
    const float* __restrict__ x_real, const float* __restrict__ x_imag,
    const float* __restrict__ params, const float* __restrict__ noise,
    const float* __restrict__ W1, const float* __restrict__ B1,
    const float* __restrict__ W2, const float* __restrict__ B2,
    float* __restrict__ out)
{
    // [dbuf][net 4][traj 16][20 floats: d 0..15 used, pad 4]
    __shared__ __attribute__((aligned(16))) float xbuf[2][4][16][20];
    __shared__ float nl[64 * 16];       // [step][traj], row 63 = row 62

    const int tid  = threadIdx.x;
    const int lane = tid & 63;
    const int l15  = lane & 15;
    const int g    = lane >> 4;
    const int wv   = tid >> 6;          // net index 0..3

    // ---- stage noise: 1008 contiguous floats -> transposed LDS ----
    {
        const float* __restrict__ nb = noise + (size_t)(blockIdx.x * 16) * NSTEP;
        #pragma unroll
        for (int k = 0; k < 4; ++k) {
            const int idx = tid + k * 256;
            if (idx < 16 * NSTEP) {
                const int traj = (idx * 4162) >> 18;     // idx/63 (magic)
                const int s    = idx - traj * 63;
                nl[s * 16 + traj] = nb[idx];
            }
        }
        if (tid < 16) {} // (row-63 fill below, after all stores)
    }

    // ---- GEMM1 A-frags: tile t, row=l15 -> h = 16t + l15 (within net wv),
    //      elem j -> state feature 8g + j; pre-scaled by TSC ----
    Frag w1f[4];
    #pragma unroll
    for (int t = 0; t < 4; ++t) {
        const int h = 16 * t + l15;
        #pragma unroll
        for (int j = 0; j < 8; ++j)
            w1f[t].v[j] = f2bf(TSC * W1[(wv * 38 + 1 + 8 * g + j) * 64 + h]);
    }

    // ---- GEMM2 A-frags (W2' = -2*W2): row=l15=d,
    //      elem j -> h_local = 16*(2kt+(j>>2)) + 4g + (j&3) ----
    Frag w2f[2];
    #pragma unroll
    for (int kt = 0; kt < 2; ++kt) {
        #pragma unroll
        for (int j = 0; j < 8; ++j) {
            const int hl = 16 * (2 * kt + (j >> 2)) + 4 * g + (j & 3);
            w2f[kt].v[j] = f2bf(-2.0f * W2[(wv * 64 + hl) * 16 + l15]);
        }
    }

    // ---- bias + t-coefficient at C-layout positions (scaled by TSC) ----
    float pr[5];
    #pragma unroll
    for (int p = 0; p < 5; ++p) pr[p] = params[p];
    f32x4 biascur[4], wtdt[4];
    #pragma unroll
    for (int t = 0; t < 4; ++t) {
        #pragma unroll
        for (int r = 0; r < 4; ++r) {
            const int h = 16 * t + 4 * g + r;
            float b = B1[wv * 64 + h];
            #pragma unroll
            for (int p = 0; p < 5; ++p)
                b = fmaf(pr[p], W1[(wv * 38 + 33 + p) * 64 + h], b);
            biascur[t][r] = TSC * b;
            wtdt[t][r]    = (TSC * DT) * W1[(wv * 38 + 0) * 64 + h];
        }
    }

    // ---- GEMM2 C-in': B2 + sum_h W2[h, d] via 2 MFMAs with B-frag -0.5 ----
    f32x4 bc;
    #pragma unroll
    for (int r = 0; r < 4; ++r) bc[r] = B2[wv * 16 + 4 * g + r];
    {
        Frag nh;
        nh.u[0] = 0xBF00BF00u;  nh.u[1] = 0xBF00BF00u;   // bf16 -0.5 x2
        nh.u[2] = 0xBF00BF00u;  nh.u[3] = 0xBF00BF00u;
        bc = __builtin_amdgcn_mfma_f32_16x16x32_bf16(w2f[0].v, nh.v, bc, 0, 0, 0);
        bc = __builtin_amdgcn_mfma_f32_16x16x32_bf16(w2f[1].v, nh.v, bc, 0, 0, 0);
    }

    // ---- state: lane holds comps 8g..8g+7 of traj n (replicated across waves) ----
    const int n    = blockIdx.x * 16 + l15;
    const int xrow = n & (NB - 1);
    const float* __restrict__ xsrc = (g < 2) ? x_real : x_imag;
    const int xoff = (g & 1) * 8;
    f32x4 stlo = *reinterpret_cast<const f32x4*>(&xsrc[xrow * 16 + xoff]);
    f32x4 sthi = *reinterpret_cast<const f32x4*>(&xsrc[xrow * 16 + xoff + 4]);

    __syncthreads();                    // noise staging visible
    if (tid < 16) nl[63 * 16 + tid] = nl[62 * 16 + tid];
    __syncthreads();                    // row-63 fill visible

    float dw = nl[l15];                 // step 0

    float* wrp           = &xbuf[0][wv][l15][4 * g];
    const float* rd_dr   = &xbuf[0][g >> 1][l15][8 * (g & 1)];
    const float* rd_df   = &xbuf[0][2 + (g >> 1)][l15][8 * (g & 1)];
    const int dstep = 4 * 16 * 20;   // floats per dbuf half

    for (int s = 0; s < NSTEP; ++s) {
        const float dwn = nl[(s + 1) * 16 + l15];   // row 63 = row 62 copy

        // state -> bf16 B-fragment (k-slot 8g+j = component 8g+j)
        Frag bx;
        bx.u[0] = pk_bf16(stlo[0], stlo[1]);
        bx.u[1] = pk_bf16(stlo[2], stlo[3]);
        bx.u[2] = pk_bf16(sthi[0], sthi[1]);
        bx.u[3] = pk_bf16(sthi[2], sthi[3]);

        // GEMM1: 4 MFMAs, C-in = scaled bias + t*w_t
        f32x4 acc[4];
        #pragma unroll
        for (int t = 0; t < 4; ++t)
            acc[t] = __builtin_amdgcn_mfma_f32_16x16x32_bf16(
                w1f[t].v, bx.v, biascur[t], 0, 0, 0);
        #pragma unroll
        for (int t = 0; t < 4; ++t) biascur[t] += wtdt[t];

        // GEMM2: u-activation (exp+add+rcp), K=64 over own net
        f32x4 o = bc;
        #pragma unroll
        for (int kt = 0; kt < 2; ++kt) {
            const float u0 = sig_u(acc[2 * kt][0]);
            const float u1 = sig_u(acc[2 * kt][1]);
            const float u2 = sig_u(acc[2 * kt][2]);
            const float u3 = sig_u(acc[2 * kt][3]);
            const float u4 = sig_u(acc[2 * kt + 1][0]);
            const float u5 = sig_u(acc[2 * kt + 1][1]);
            const float u6 = sig_u(acc[2 * kt + 1][2]);
            const float u7 = sig_u(acc[2 * kt + 1][3]);
            Frag pb;
            pb.u[0] = pk_bf16(u0, u1);  pb.u[1] = pk_bf16(u2, u3);
            pb.u[2] = pk_bf16(u4, u5);  pb.u[3] = pk_bf16(u6, u7);
            o = __builtin_amdgcn_mfma_f32_16x16x32_bf16(w2f[kt].v, pb.v, o, 0, 0, 0);
        }

        // ---- exchange: write own net's 4 outputs, read all 4 nets ----
        const int db = s & 1;
        *reinterpret_cast<f32x4*>(wrp + db * dstep) = o;
        __syncthreads();
        const float* dp = rd_dr + db * dstep;
        const float* fp = rd_df + db * dstep;
        const f32x4 dr0 = *reinterpret_cast<const f32x4*>(dp);
        const f32x4 dr1 = *reinterpret_cast<const f32x4*>(dp + 4);
        const f32x4 df0 = *reinterpret_cast<const f32x4*>(fp);
        const f32x4 df1 = *reinterpret_cast<const f32x4*>(fp + 4);

        // Euler-Maruyama, packed v_pk_fma
        const f32x4 dt4 = (f32x4)DT;
        const f32x4 dw4 = (f32x4)dw;
        stlo = __builtin_elementwise_fma(dt4, dr0,
               __builtin_elementwise_fma(dw4, df0, stlo));
        sthi = __builtin_elementwise_fma(dt4, dr1,
               __builtin_elementwise_fma(dw4, df1, sthi));
        dw = dwn;
    }

    // ---- write out (wave 0 only): lane holds comps 8g..8g+7 of traj n ----
    if (wv == 0) {
        float4* op = reinterpret_cast<float4*>(out + (size_t)n * 32 + 8 * g);
        op[0] = make_float4(stlo[0], stlo[1], stlo[2], stlo[3]);
        op[1] = make_float4(sthi[0], sthi[1], sthi[2], sthi[3]);
    }
}

extern "C" void kernel_launch(void* const* d_in, const int* in_sizes, int n_in,
                              void* d_out, int out_size, void* d_ws, size_t ws_size,
                              hipStream_t stream) {
    const float* x_real = (const float*)d_in[0];
    const float* x_imag = (const float*)d_in[1];
    const float* params = (const float*)d_in[2];
    const float* noise  = (const float*)d_in[3];
    const float* W1     = (const float*)d_in[4];
    const float* B1     = (const float*)d_in[5];
    const float* W2     = (const float*)d_in[6];
    const float* B2     = (const float*)d_in[7];
    float* out = (float*)d_out;

    // 1024 blocks x 256 threads: 4 waves/block, one 16-traj group per block
    sde_nlds<<<dim3(1024), dim3(256), 0, stream>>>(
        x_real, x_imag, params, noise, W1, B1, W2, B2, out);
}

// Round 14
// 77.851 us; speedup vs baseline: 1.4671x; 1.0040x over previous
//
#include <hip/hip_runtime.h>
#include <stdint.h>

#define NB    128
#define NSTEP 63
#define DT    0.00390625f
#define TSC   2.8853900817779268f   // 2*log2(e): folded into GEMM1 weights

typedef __attribute__((ext_vector_type(8))) short bf16x8;
typedef __attribute__((ext_vector_type(4))) float f32x4;

union Frag { bf16x8 v; uint32_t u[4]; };

__device__ __forceinline__ short f2bf(float f) {
    uint32_t u = __float_as_uint(f);
    u += 0x7FFF + ((u >> 16) & 1);          // round-to-nearest-even
    return (short)(u >> 16);
}

__device__ __forceinline__ uint32_t pk_bf16(float lo, float hi) {
    uint32_t r;
    asm("v_cvt_pk_bf16_f32 %0, %1, %2" : "=v"(r) : "v"(lo), "v"(hi));
    return r;
}

// u = 1/(2^y + 1) with y = 2*log2e*preact (TSC folded into GEMM1 weights).
// tanh = 1 - 2u; affine part folded into GEMM2 (W2' = -2*W2, C-in' = B2 +
// sum_h W2[h,:] via 2 init MFMAs). Builtins only (inline-asm exp broke R3).
__device__ __forceinline__ float sig_u(float y) {
    float e = __builtin_amdgcn_exp2f(y);
    return __builtin_amdgcn_rcpf(e + 1.0f);
}

// R13 (78.2 us) + CONFLICT-FREE EXCHANGE LAYOUT:
// old xbuf[net][traj][20] stride-20 rows alias banks (l15 vs l15+8 collide
// on the b128 write; 4.55M conflict cycles ~ 9.5% of runtime). New layout
// f32x4 xbuf4[dbuf][16][16]: write row wv*4+g, col l15 -> the wave's 64
// lanes hit consecutive f32x4 slots (perfect stripe); read rows
// net*4+2*(g&1) (+1) are 16-lane-consecutive groups. Zero conflicts by
// construction. Noise slice also LDS-staged (R13), transposed nl[s][traj].
__global__ __launch_bounds__(256, 4) void sde_xfree(
    const float* __restrict__ x_real, const float* __restrict__ x_imag,
    const float* __restrict__ params, const float* __restrict__ noise,
    const float* __restrict__ W1, const float* __restrict__ B1,
    const float* __restrict__ W2, const float* __restrict__ B2,
    float* __restrict__ out)
{
    __shared__ f32x4 xbuf4[2][16][16];   // [dbuf][row=net*4+dim4][traj]
    __shared__ float nl[64 * 16];        // [step][traj], row 63 = row 62

    const int tid  = threadIdx.x;
    const int lane = tid & 63;
    const int l15  = lane & 15;
    const int g    = lane >> 4;
    const int wv   = tid >> 6;          // net index 0..3

    // ---- stage noise: 1008 contiguous floats -> transposed LDS ----
    {
        const float* __restrict__ nb = noise + (size_t)(blockIdx.x * 16) * NSTEP;
        #pragma unroll
        for (int k = 0; k < 4; ++k) {
            const int idx = tid + k * 256;
            if (idx < 16 * NSTEP) {
                const int traj = (idx * 4162) >> 18;     // idx/63 (magic)
                const int s    = idx - traj * 63;
                nl[s * 16 + traj] = nb[idx];
            }
        }
    }

    // ---- GEMM1 A-frags: tile t, row=l15 -> h = 16t + l15 (within net wv),
    //      elem j -> state feature 8g + j; pre-scaled by TSC ----
    Frag w1f[4];
    #pragma unroll
    for (int t = 0; t < 4; ++t) {
        const int h = 16 * t + l15;
        #pragma unroll
        for (int j = 0; j < 8; ++j)
            w1f[t].v[j] = f2bf(TSC * W1[(wv * 38 + 1 + 8 * g + j) * 64 + h]);
    }

    // ---- GEMM2 A-frags (W2' = -2*W2): row=l15=d,
    //      elem j -> h_local = 16*(2kt+(j>>2)) + 4g + (j&3) ----
    Frag w2f[2];
    #pragma unroll
    for (int kt = 0; kt < 2; ++kt) {
        #pragma unroll
        for (int j = 0; j < 8; ++j) {
            const int hl = 16 * (2 * kt + (j >> 2)) + 4 * g + (j & 3);
            w2f[kt].v[j] = f2bf(-2.0f * W2[(wv * 64 + hl) * 16 + l15]);
        }
    }

    // ---- bias + t-coefficient at C-layout positions (scaled by TSC) ----
    float pr[5];
    #pragma unroll
    for (int p = 0; p < 5; ++p) pr[p] = params[p];
    f32x4 biascur[4], wtdt[4];
    #pragma unroll
    for (int t = 0; t < 4; ++t) {
        #pragma unroll
        for (int r = 0; r < 4; ++r) {
            const int h = 16 * t + 4 * g + r;
            float b = B1[wv * 64 + h];
            #pragma unroll
            for (int p = 0; p < 5; ++p)
                b = fmaf(pr[p], W1[(wv * 38 + 33 + p) * 64 + h], b);
            biascur[t][r] = TSC * b;
            wtdt[t][r]    = (TSC * DT) * W1[(wv * 38 + 0) * 64 + h];
        }
    }

    // ---- GEMM2 C-in': B2 + sum_h W2[h, d] via 2 MFMAs with B-frag -0.5 ----
    f32x4 bc;
    #pragma unroll
    for (int r = 0; r < 4; ++r) bc[r] = B2[wv * 16 + 4 * g + r];
    {
        Frag nh;
        nh.u[0] = 0xBF00BF00u;  nh.u[1] = 0xBF00BF00u;   // bf16 -0.5 x2
        nh.u[2] = 0xBF00BF00u;  nh.u[3] = 0xBF00BF00u;
        bc = __builtin_amdgcn_mfma_f32_16x16x32_bf16(w2f[0].v, nh.v, bc, 0, 0, 0);
        bc = __builtin_amdgcn_mfma_f32_16x16x32_bf16(w2f[1].v, nh.v, bc, 0, 0, 0);
    }

    // ---- state: lane holds comps 8g..8g+7 of traj n (replicated across waves) ----
    const int n    = blockIdx.x * 16 + l15;
    const int xrow = n & (NB - 1);
    const float* __restrict__ xsrc = (g < 2) ? x_real : x_imag;
    const int xoff = (g & 1) * 8;
    f32x4 stlo = *reinterpret_cast<const f32x4*>(&xsrc[xrow * 16 + xoff]);
    f32x4 sthi = *reinterpret_cast<const f32x4*>(&xsrc[xrow * 16 + xoff + 4]);

    __syncthreads();                    // noise staging visible
    if (tid < 16) nl[63 * 16 + tid] = nl[62 * 16 + tid];
    __syncthreads();                    // row-63 fill visible

    float dw = nl[l15];                 // step 0

    // exchange rows: write wv*4+g; read net*4 + 2*(g&1) (+1), nets g>>1, 2+(g>>1)
    const int wrow  = wv * 4 + g;
    const int r_dr  = (g >> 1) * 4 + 2 * (g & 1);
    const int r_df  = (2 + (g >> 1)) * 4 + 2 * (g & 1);

    for (int s = 0; s < NSTEP; ++s) {
        const float dwn = nl[(s + 1) * 16 + l15];   // row 63 = row 62 copy

        // state -> bf16 B-fragment (k-slot 8g+j = component 8g+j)
        Frag bx;
        bx.u[0] = pk_bf16(stlo[0], stlo[1]);
        bx.u[1] = pk_bf16(stlo[2], stlo[3]);
        bx.u[2] = pk_bf16(sthi[0], sthi[1]);
        bx.u[3] = pk_bf16(sthi[2], sthi[3]);

        // GEMM1: 4 MFMAs, C-in = scaled bias + t*w_t
        f32x4 acc[4];
        #pragma unroll
        for (int t = 0; t < 4; ++t)
            acc[t] = __builtin_amdgcn_mfma_f32_16x16x32_bf16(
                w1f[t].v, bx.v, biascur[t], 0, 0, 0);
        #pragma unroll
        for (int t = 0; t < 4; ++t) biascur[t] += wtdt[t];

        // GEMM2: u-activation (exp+add+rcp), K=64 over own net
        f32x4 o = bc;
        #pragma unroll
        for (int kt = 0; kt < 2; ++kt) {
            const float u0 = sig_u(acc[2 * kt][0]);
            const float u1 = sig_u(acc[2 * kt][1]);
            const float u2 = sig_u(acc[2 * kt][2]);
            const float u3 = sig_u(acc[2 * kt][3]);
            const float u4 = sig_u(acc[2 * kt + 1][0]);
            const float u5 = sig_u(acc[2 * kt + 1][1]);
            const float u6 = sig_u(acc[2 * kt + 1][2]);
            const float u7 = sig_u(acc[2 * kt + 1][3]);
            Frag pb;
            pb.u[0] = pk_bf16(u0, u1);  pb.u[1] = pk_bf16(u2, u3);
            pb.u[2] = pk_bf16(u4, u5);  pb.u[3] = pk_bf16(u6, u7);
            o = __builtin_amdgcn_mfma_f32_16x16x32_bf16(w2f[kt].v, pb.v, o, 0, 0, 0);
        }

        // ---- exchange: conflict-free consecutive-lane layout ----
        const int db = s & 1;
        xbuf4[db][wrow][l15] = o;
        __syncthreads();
        const f32x4 dr0 = xbuf4[db][r_dr][l15];
        const f32x4 dr1 = xbuf4[db][r_dr + 1][l15];
        const f32x4 df0 = xbuf4[db][r_df][l15];
        const f32x4 df1 = xbuf4[db][r_df + 1][l15];

        // Euler-Maruyama, packed v_pk_fma
        const f32x4 dt4 = (f32x4)DT;
        const f32x4 dw4 = (f32x4)dw;
        stlo = __builtin_elementwise_fma(dt4, dr0,
               __builtin_elementwise_fma(dw4, df0, stlo));
        sthi = __builtin_elementwise_fma(dt4, dr1,
               __builtin_elementwise_fma(dw4, df1, sthi));
        dw = dwn;
    }

    // ---- write out (wave 0 only): lane holds comps 8g..8g+7 of traj n ----
    if (wv == 0) {
        float4* op = reinterpret_cast<float4*>(out + (size_t)n * 32 + 8 * g);
        op[0] = make_float4(stlo[0], stlo[1], stlo[2], stlo[3]);
        op[1] = make_float4(sthi[0], sthi[1], sthi[2], sthi[3]);
    }
}

extern "C" void kernel_launch(void* const* d_in, const int* in_sizes, int n_in,
                              void* d_out, int out_size, void* d_ws, size_t ws_size,
                              hipStream_t stream) {
    const float* x_real = (const float*)d_in[0];
    const float* x_imag = (const float*)d_in[1];
    const float* params = (const float*)d_in[2];
    const float* noise  = (const float*)d_in[3];
    const float* W1     = (const float*)d_in[4];
    const float* B1     = (const float*)d_in[5];
    const float* W2     = (const float*)d_in[6];
    const float* B2     = (const float*)d_in[7];
    float* out = (float*)d_out;

    // 1024 blocks x 256 threads: 4 waves/block, one 16-traj group per block
    sde_xfree<<<dim3(1024), dim3(256), 0, stream>>>(
        x_real, x_imag, params, noise, W1, B1, W2, B2, out);
}